// Round 2
// baseline (916.699 us; speedup 1.0000x reference)
//
#include <hip/hip_runtime.h>
#include <hip/hip_bf16.h>

#define T_TOK 8192
#define NSLOT 16384
#define DM 512
#define DF 2048
#define NEXP 64
#define CAP 320
#define MP 384   // padded rows per expert (3 x 128 tiles)

typedef __bf16 bf16_t;
typedef __bf16 bf16x8 __attribute__((ext_vector_type(8)));
typedef float floatx4 __attribute__((ext_vector_type(4)));

__device__ __forceinline__ void load_lds16(const bf16_t* g, bf16_t* l) {
    __builtin_amdgcn_global_load_lds(
        (const __attribute__((address_space(1))) void*)g,
        (__attribute__((address_space(3))) void*)l, 16, 0, 0);
}

// ---------------- K1: scores -> expert ids (hash 0,1 only); also init inv = -1
__global__ __launch_bounds__(256) void k_scores(const float* __restrict__ x,
        const float* __restrict__ Wh, int* __restrict__ e_arr, int* __restrict__ inv)
{
    int tid = threadIdx.x;
    if (tid < 10) inv[blockIdx.x * 10 + tid] = -1;   // 2048*10 = 20480 = NEXP*CAP
    int wid = tid >> 6, lane = tid & 63;
    int t = blockIdx.x * 4 + wid;
    const float4* xp = (const float4*)(x + (size_t)t * DM);
    float4 x0 = xp[lane * 2], x1 = xp[lane * 2 + 1];
    const float4* w0p = (const float4*)(Wh);
    const float4* w1p = (const float4*)(Wh + DM);
    float4 a0 = w0p[lane * 2], a1 = w0p[lane * 2 + 1];
    float4 b0 = w1p[lane * 2], b1 = w1p[lane * 2 + 1];
    float s0 = x0.x*a0.x + x0.y*a0.y + x0.z*a0.z + x0.w*a0.w
             + x1.x*a1.x + x1.y*a1.y + x1.z*a1.z + x1.w*a1.w;
    float s1 = x0.x*b0.x + x0.y*b0.y + x0.z*b0.z + x0.w*b0.w
             + x1.x*b1.x + x1.y*b1.y + x1.z*b1.z + x1.w*b1.w;
    #pragma unroll
    for (int off = 32; off; off >>= 1) {
        s0 += __shfl_xor(s0, off);
        s1 += __shfl_xor(s1, off);
    }
    if (lane == 0) {
        int q0 = ((int)floorf(s0 * 8.0f)) & 63;   // python mod 64 == &63
        int q1 = ((int)floorf(s1 * 8.0f)) & 63;
        e_arr[2 * t]     = q0;
        e_arr[2 * t + 1] = q1;
    }
}

// ---------------- K2: per-256-slot-chunk histogram + stable local rank
__global__ __launch_bounds__(256) void k_hist(const int* __restrict__ e_arr,
        int* __restrict__ rank_arr, int* __restrict__ hist_g)
{
    __shared__ int se[256];
    __shared__ int hist[64];
    int tid = threadIdx.x;
    if (tid < 64) hist[tid] = 0;
    __syncthreads();
    int s = blockIdx.x * 256 + tid;
    int e = e_arr[s];
    se[tid] = e;
    atomicAdd(&hist[e], 1);
    __syncthreads();
    int cnt = 0;
    for (int j = 0; j < 255; ++j)
        if (j < tid && se[j] == e) cnt++;
    rank_arr[s] = cnt;
    if (tid < 64) hist_g[blockIdx.x * 64 + tid] = hist[tid];
}

// ---------------- K3: exclusive scan over chunks -> global pos; build inverse map
__global__ __launch_bounds__(256) void k_pos(const int* __restrict__ e_arr,
        const int* __restrict__ rank_arr, const int* __restrict__ hist_g,
        int* __restrict__ pos_arr, int* __restrict__ inv)
{
    __shared__ int base[64][64];   // [chunk][expert]
    int tid = threadIdx.x;
    if (tid < 64) {
        int run = 0;
        for (int c = 0; c < 64; ++c) {
            base[c][tid] = run;
            run += hist_g[c * 64 + tid];
        }
    }
    __syncthreads();
    for (int i = 0; i < 64; ++i) {
        int s = i * 256 + tid;
        int e = e_arr[s];
        int p = base[s >> 8][e] + rank_arr[s];
        pos_arr[s] = p;
        if (p < CAP) inv[e * CAP + p] = s;
    }
}

// ---------------- K4: build buf (bf16, MP rows/expert), zero unfilled/pad rows.
__global__ __launch_bounds__(256) void k_buf(const float* __restrict__ x,
        const int* __restrict__ inv, bf16_t* __restrict__ buf)
{
    int tid = threadIdx.x;
    int r = blockIdx.x * 4 + (tid >> 6);     // 0 .. 64*MP-1
    int lane = tid & 63;
    int e = r / MP, row = r % MP;
    int s = (row < CAP) ? inv[e * CAP + row] : -1;
    union { uint4 u; bf16_t h[8]; } pk;
    if (s >= 0) {
        int t = s >> 1;
        const float* xr = x + (size_t)t * DM + lane * 8;
        float4 f0 = *(const float4*)xr;
        float4 f1 = *(const float4*)(xr + 4);
        pk.h[0] = (bf16_t)f0.x; pk.h[1] = (bf16_t)f0.y;
        pk.h[2] = (bf16_t)f0.z; pk.h[3] = (bf16_t)f0.w;
        pk.h[4] = (bf16_t)f1.x; pk.h[5] = (bf16_t)f1.y;
        pk.h[6] = (bf16_t)f1.z; pk.h[7] = (bf16_t)f1.w;
    } else {
        pk.u.x = 0; pk.u.y = 0; pk.u.z = 0; pk.u.w = 0;
    }
    *(uint4*)(buf + (size_t)r * DM + lane * 8) = pk.u;
}

// ---------------- K5: transpose+convert W [E][K][N] fp32 -> WT [E][N][K] bf16
template<int K_DIM, int N_DIM>
__global__ __launch_bounds__(256) void k_tcvt(const float* __restrict__ W,
                                              bf16_t* __restrict__ WT)
{
    constexpr int KT = K_DIM / 64, NTT = N_DIM / 64;
    int b = blockIdx.x;
    int e = b / (KT * NTT);
    int rem = b % (KT * NTT);
    int kt = rem / NTT, nb = rem % NTT;
    const float* We = W + (size_t)e * K_DIM * N_DIM;
    bf16_t* Oe = WT + (size_t)e * N_DIM * K_DIM;
    __shared__ float tile[64][68];   // stride 68: 16B-aligned float4 rows
    int tid = threadIdx.x;
    {
        int kl = tid >> 2, ng = (tid & 3) * 16;
        const float* src = We + (size_t)(kt * 64 + kl) * N_DIM + nb * 64 + ng;
        float4 v0 = ((const float4*)src)[0];
        float4 v1 = ((const float4*)src)[1];
        float4 v2 = ((const float4*)src)[2];
        float4 v3 = ((const float4*)src)[3];
        *(float4*)&tile[kl][ng]      = v0;
        *(float4*)&tile[kl][ng + 4]  = v1;
        *(float4*)&tile[kl][ng + 8]  = v2;
        *(float4*)&tile[kl][ng + 12] = v3;
    }
    __syncthreads();
    {
        int nl = tid >> 2, kg = (tid & 3) * 16;
        union { uint4 u[2]; bf16_t h[16]; } pk;
        #pragma unroll
        for (int i = 0; i < 16; ++i) pk.h[i] = (bf16_t)tile[kg + i][nl];
        bf16_t* dst = Oe + (size_t)(nb * 64 + nl) * K_DIM + kt * 64 + kg;
        *(uint4*)dst       = pk.u[0];
        *(uint4*)(dst + 8) = pk.u[1];
    }
}

// ---------------- GEMM: C[e](M_TOT x N) = act(A[e](bf16 [MP][K]) @ B[e](bf16 [N][K])^T + bias)
// m97 structure: global_load_lds(16B) staging, XOR-granule swizzled LDS, 128x128x64 tiles.
template<int M_TOT, int OSTR, int N_DIM, int K_DIM, bool GELU, bool OUT_BF16>
__global__ __launch_bounds__(256) void gemm_tc(const bf16_t* __restrict__ A,
        const bf16_t* __restrict__ B, const float* __restrict__ bias,
        void* __restrict__ OutP)
{
    constexpr int MT = (M_TOT + 127) / 128;
    constexpr int NT = N_DIM / 128;
    int bx = blockIdx.x;
    int e  = bx / (MT * NT);
    int rem = bx % (MT * NT);
    int mt = rem / NT;
    int nt = rem % NT;

    const bf16_t* Ae = A + (size_t)e * MP * K_DIM + (size_t)mt * 128 * K_DIM;
    const bf16_t* Be = B + (size_t)e * N_DIM * K_DIM + (size_t)nt * 128 * K_DIM;
    const float*  be = bias + (size_t)e * N_DIM;

    // [128 rows][64 k] bf16, granule(16B)-swizzled: phys_g = row*8 + (g ^ (row&7))
    __shared__ __align__(16) bf16_t As[128 * 64];
    __shared__ __align__(16) bf16_t Bs[128 * 64];

    int tid = threadIdx.x;
    int lane = tid & 63;
    int wid = tid >> 6;
    int qm = lane & 15;
    int quad = lane >> 4;
    int wm = (wid >> 1) * 64;
    int wn = (wid & 1) * 64;

    int srow = lane >> 3;                 // 0..7 within chunk
    int gl = (lane & 7) ^ srow;           // logical granule this lane fetches

    floatx4 acc[4][4];
    #pragma unroll
    for (int i = 0; i < 4; ++i)
        #pragma unroll
        for (int j = 0; j < 4; ++j) acc[i][j] = (floatx4)0.0f;

    for (int kk = 0; kk < K_DIM; kk += 64) {
        #pragma unroll
        for (int c = 0; c < 4; ++c) {
            int q = wid * 4 + c;              // chunk: rows q*8 .. q*8+7
            int row = q * 8 + srow;
            load_lds16(Ae + (size_t)row * K_DIM + kk + gl * 8, As + q * 512);
            load_lds16(Be + (size_t)row * K_DIM + kk + gl * 8, Bs + q * 512);
        }
        __syncthreads();
        #pragma unroll
        for (int ks = 0; ks < 2; ++ks) {
            bf16x8 af[4], bfr[4];
            #pragma unroll
            for (int i = 0; i < 4; ++i) {
                int r = wm + i * 16 + qm;
                int pg = r * 8 + ((ks * 4 + quad) ^ (r & 7));
                af[i] = *(const bf16x8*)(As + pg * 8);
            }
            #pragma unroll
            for (int j = 0; j < 4; ++j) {
                int r = wn + j * 16 + qm;
                int pg = r * 8 + ((ks * 4 + quad) ^ (r & 7));
                bfr[j] = *(const bf16x8*)(Bs + pg * 8);
            }
            #pragma unroll
            for (int i = 0; i < 4; ++i)
                #pragma unroll
                for (int j = 0; j < 4; ++j)
                    acc[i][j] = __builtin_amdgcn_mfma_f32_16x16x32_bf16(
                        af[i], bfr[j], acc[i][j], 0, 0, 0);
        }
        __syncthreads();
    }

    // epilogue: C/D layout col = lane&15, row = quad*4 + r
    #pragma unroll
    for (int j = 0; j < 4; ++j) {
        int gn = nt * 128 + wn + j * 16 + qm;
        float bz = be[gn];
        #pragma unroll
        for (int i = 0; i < 4; ++i) {
            int rowBase = mt * 128 + wm + i * 16 + quad * 4;
            #pragma unroll
            for (int r = 0; r < 4; ++r) {
                int gm = rowBase + r;
                if (gm < M_TOT) {
                    float v = acc[i][j][r] + bz;
                    if (GELU) v = 0.5f * v * (1.0f + erff(v * 0.70710678118654752f));
                    size_t idx = ((size_t)e * OSTR + gm) * N_DIM + gn;
                    if (OUT_BF16) ((bf16_t*)OutP)[idx] = (bf16_t)v;
                    else          ((float*)OutP)[idx]  = v;
                }
            }
        }
    }
}

// ---------------- K7: gather + mean over the two slots
__global__ __launch_bounds__(256) void k_gather(const float* __restrict__ y,
        const int* __restrict__ e_arr, const int* __restrict__ pos_arr,
        float* __restrict__ out)
{
    int tid = threadIdx.x;
    int t = blockIdx.x * 4 + (tid >> 6);
    int lane = tid & 63;
    float a[8];
    #pragma unroll
    for (int i = 0; i < 8; ++i) a[i] = 0.0f;
    #pragma unroll
    for (int k = 0; k < 2; ++k) {
        int s = 2 * t + k;
        int e = e_arr[s], p = pos_arr[s];
        if (p < CAP) {
            const float* yr = y + ((size_t)e * CAP + p) * DM + lane * 8;
            float4 f0 = *(const float4*)yr;
            float4 f1 = *(const float4*)(yr + 4);
            a[0] += f0.x; a[1] += f0.y; a[2] += f0.z; a[3] += f0.w;
            a[4] += f1.x; a[5] += f1.y; a[6] += f1.z; a[7] += f1.w;
        }
    }
    float4 o0, o1;
    o0.x = a[0] * 0.5f; o0.y = a[1] * 0.5f; o0.z = a[2] * 0.5f; o0.w = a[3] * 0.5f;
    o1.x = a[4] * 0.5f; o1.y = a[5] * 0.5f; o1.z = a[6] * 0.5f; o1.w = a[7] * 0.5f;
    float* orow = out + (size_t)t * DM + lane * 8;
    *(float4*)orow = o0;
    *(float4*)(orow + 4) = o1;
}

extern "C" void kernel_launch(void* const* d_in, const int* in_sizes, int n_in,
                              void* d_out, int out_size, void* d_ws, size_t ws_size,
                              hipStream_t stream)
{
    const float* x  = (const float*)d_in[0];
    const float* Wh = (const float*)d_in[1];
    const float* W1 = (const float*)d_in[2];
    const float* b1 = (const float*)d_in[3];
    const float* W2 = (const float*)d_in[4];
    const float* b2 = (const float*)d_in[5];
    float* out = (float*)d_out;

    char* p = (char*)d_ws;
    int*    e_arr  = (int*)p;    p += (size_t)NSLOT * 4;
    int*    rank_a = (int*)p;    p += (size_t)NSLOT * 4;
    int*    hist_g = (int*)p;    p += (size_t)64 * 64 * 4;
    int*    pos_a  = (int*)p;    p += (size_t)NSLOT * 4;
    int*    inv    = (int*)p;    p += (size_t)NEXP * CAP * 4;
    // buf (bf16, 25.2MB) and ybuf (fp32, 41.9MB) overlap: buf dead before GEMM2 writes ybuf
    bf16_t* buf    = (bf16_t*)p;
    float*  ybuf   = (float*)p;  p += (size_t)NEXP * CAP * DM * 4;
    bf16_t* hbuf   = (bf16_t*)p; p += (size_t)NEXP * MP * DF * 2;
    bf16_t* wT     = (bf16_t*)p; p += (size_t)NEXP * DM * DF * 2;   // shared W1T then W2T

    k_scores<<<2048, 256, 0, stream>>>(x, Wh, e_arr, inv);
    k_hist<<<64, 256, 0, stream>>>(e_arr, rank_a, hist_g);
    k_pos<<<1, 256, 0, stream>>>(e_arr, rank_a, hist_g, pos_a, inv);
    k_buf<<<NEXP * MP / 4, 256, 0, stream>>>(x, inv, buf);

    // W1 [e][512][2048] fp32 -> wT [e][2048][512] bf16 ; GEMM1
    k_tcvt<DM, DF><<<NEXP * (DM / 64) * (DF / 64), 256, 0, stream>>>(W1, wT);
    gemm_tc<CAP, MP, DF, DM, true, true>
        <<<NEXP * 3 * (DF / 128), 256, 0, stream>>>(buf, wT, b1, (void*)hbuf);

    // W2 [e][2048][512] fp32 -> wT [e][512][2048] bf16 ; GEMM2
    k_tcvt<DF, DM><<<NEXP * (DF / 64) * (DM / 64), 256, 0, stream>>>(W2, wT);
    gemm_tc<CAP, CAP, DM, DF, false, false>
        <<<NEXP * 3 * (DM / 128), 256, 0, stream>>>(hbuf, wT, b2, (void*)ybuf);

    k_gather<<<2048, 256, 0, stream>>>(ybuf, e_arr, pos_a, out);
}

// Round 3
// 902.713 us; speedup vs baseline: 1.0155x; 1.0155x over previous
//
#include <hip/hip_runtime.h>
#include <hip/hip_bf16.h>

#define T_TOK 8192
#define NSLOT 16384
#define DM 512
#define DF 2048
#define NEXP 64
#define CAP 320
#define MP 384   // padded rows per expert (3 x 128 tiles)

typedef __bf16 bf16_t;
typedef __bf16 bf16x8 __attribute__((ext_vector_type(8)));
typedef float floatx4 __attribute__((ext_vector_type(4)));

// ---------------- K1: scores -> expert ids (hash 0,1 only); also init inv = -1
__global__ __launch_bounds__(256) void k_scores(const float* __restrict__ x,
        const float* __restrict__ Wh, int* __restrict__ e_arr, int* __restrict__ inv)
{
    int tid = threadIdx.x;
    if (tid < 10) inv[blockIdx.x * 10 + tid] = -1;   // 2048*10 = 20480 = NEXP*CAP
    int wid = tid >> 6, lane = tid & 63;
    int t = blockIdx.x * 4 + wid;
    const float4* xp = (const float4*)(x + (size_t)t * DM);
    float4 x0 = xp[lane * 2], x1 = xp[lane * 2 + 1];
    const float4* w0p = (const float4*)(Wh);
    const float4* w1p = (const float4*)(Wh + DM);
    float4 a0 = w0p[lane * 2], a1 = w0p[lane * 2 + 1];
    float4 b0 = w1p[lane * 2], b1 = w1p[lane * 2 + 1];
    float s0 = x0.x*a0.x + x0.y*a0.y + x0.z*a0.z + x0.w*a0.w
             + x1.x*a1.x + x1.y*a1.y + x1.z*a1.z + x1.w*a1.w;
    float s1 = x0.x*b0.x + x0.y*b0.y + x0.z*b0.z + x0.w*b0.w
             + x1.x*b1.x + x1.y*b1.y + x1.z*b1.z + x1.w*b1.w;
    #pragma unroll
    for (int off = 32; off; off >>= 1) {
        s0 += __shfl_xor(s0, off);
        s1 += __shfl_xor(s1, off);
    }
    if (lane == 0) {
        int q0 = ((int)floorf(s0 * 8.0f)) & 63;   // python mod 64 == &63
        int q1 = ((int)floorf(s1 * 8.0f)) & 63;
        e_arr[2 * t]     = q0;
        e_arr[2 * t + 1] = q1;
    }
}

// ---------------- K2: per-256-slot-chunk histogram + stable local rank
__global__ __launch_bounds__(256) void k_hist(const int* __restrict__ e_arr,
        int* __restrict__ rank_arr, int* __restrict__ hist_g)
{
    __shared__ int se[256];
    __shared__ int hist[64];
    int tid = threadIdx.x;
    if (tid < 64) hist[tid] = 0;
    __syncthreads();
    int s = blockIdx.x * 256 + tid;
    int e = e_arr[s];
    se[tid] = e;
    atomicAdd(&hist[e], 1);
    __syncthreads();
    int cnt = 0;
    for (int j = 0; j < 255; ++j)
        if (j < tid && se[j] == e) cnt++;
    rank_arr[s] = cnt;
    if (tid < 64) hist_g[blockIdx.x * 64 + tid] = hist[tid];
}

// ---------------- K3: one block per chunk; prefix over earlier chunks -> pos + inverse map
__global__ __launch_bounds__(256) void k_pos(const int* __restrict__ e_arr,
        const int* __restrict__ rank_arr, const int* __restrict__ hist_g,
        int* __restrict__ pos_arr, int* __restrict__ inv)
{
    __shared__ int base[64];
    int tid = threadIdx.x, c = blockIdx.x;
    if (tid < 64) {
        int run = 0;
        for (int cc = 0; cc < c; ++cc) run += hist_g[cc * 64 + tid];
        base[tid] = run;
    }
    __syncthreads();
    int s = c * 256 + tid;
    int e = e_arr[s];
    int p = base[e] + rank_arr[s];
    pos_arr[s] = p;
    if (p < CAP) inv[e * CAP + p] = s;
}

// ---------------- K4: build buf (bf16, MP rows/expert), zero unfilled/pad rows.
__global__ __launch_bounds__(256) void k_buf(const float* __restrict__ x,
        const int* __restrict__ inv, bf16_t* __restrict__ buf)
{
    int tid = threadIdx.x;
    int r = blockIdx.x * 4 + (tid >> 6);     // 0 .. 64*MP-1
    int lane = tid & 63;
    int e = r / MP, row = r % MP;
    int s = (row < CAP) ? inv[e * CAP + row] : -1;
    union { uint4 u; bf16_t h[8]; } pk;
    if (s >= 0) {
        int t = s >> 1;
        const float* xr = x + (size_t)t * DM + lane * 8;
        float4 f0 = *(const float4*)xr;
        float4 f1 = *(const float4*)(xr + 4);
        pk.h[0] = (bf16_t)f0.x; pk.h[1] = (bf16_t)f0.y;
        pk.h[2] = (bf16_t)f0.z; pk.h[3] = (bf16_t)f0.w;
        pk.h[4] = (bf16_t)f1.x; pk.h[5] = (bf16_t)f1.y;
        pk.h[6] = (bf16_t)f1.z; pk.h[7] = (bf16_t)f1.w;
    } else {
        pk.u.x = 0; pk.u.y = 0; pk.u.z = 0; pk.u.w = 0;
    }
    *(uint4*)(buf + (size_t)r * DM + lane * 8) = pk.u;
}

// ---------------- Fused GEMM: C[e] = act(A[e](bf16 [MP][K]) @ B[e](fp32 [K][N]) + bias)
// Register-prefetch pipeline: next K-tile's A/B loaded into VGPRs during current
// MFMA section; LDS staged via ds_write (XOR-granule swizzle, conflict-free).
// MFMA operands swapped -> lane&15 = m (row), quad*4+r = n (col): vector epilogue.
template<int M_TOT, int OSTR, int N_DIM, int K_DIM, bool GELU, bool OUT_BF16>
__global__ __launch_bounds__(256) void gemm_fused(const bf16_t* __restrict__ A,
        const float* __restrict__ B, const float* __restrict__ bias,
        void* __restrict__ OutP)
{
    constexpr int MT = (M_TOT + 127) / 128;
    constexpr int NT = N_DIM / 128;
    int bx = blockIdx.x;
    int e  = bx / (MT * NT);
    int rem = bx % (MT * NT);
    int mt = rem / NT;
    int nt = rem % NT;

    const bf16_t* Ae = A + (size_t)e * MP * K_DIM + (size_t)mt * 128 * K_DIM;
    const float*  Be = B + (size_t)e * K_DIM * N_DIM + nt * 128;
    const float*  be = bias + (size_t)e * N_DIM + nt * 128;

    __shared__ __align__(16) bf16_t As[128 * 64];  // granule g=16B: phys = row*8 + (g ^ (row&7))
    __shared__ __align__(16) bf16_t Bs[128 * 64];

    int tid = threadIdx.x;
    int lane = tid & 63;
    int wid = tid >> 6;
    int qm = lane & 15;
    int quad = lane >> 4;
    int wm = (wid >> 1) * 64;
    int wn = (wid & 1) * 64;

    // A staging: wave wid covers rows wid*32 .. wid*32+31 (4 chunks of 8 rows)
    int srow = lane >> 3;                // 0..7
    int gl = (lane & 7) ^ srow;          // logical k-granule this lane fetches
    const bf16_t* aPtr = Ae + (size_t)(wid * 32 + srow) * K_DIM + gl * 8;

    // B staging: thread covers rows (k) bkg*8..+7, cols bn..bn+3
    int bkg = tid & 7;
    int bn  = (tid >> 3) * 4;            // 0..124
    const float* bPtr = Be + (size_t)(bkg * 8) * N_DIM + bn;

    uint4  aR[4];
    float4 bR[8];
    #pragma unroll
    for (int c = 0; c < 4; ++c)
        aR[c] = *(const uint4*)(aPtr + (size_t)c * 8 * K_DIM);
    #pragma unroll
    for (int p = 0; p < 8; ++p)
        bR[p] = *(const float4*)(bPtr + (size_t)p * N_DIM);

    floatx4 acc[4][4];
    #pragma unroll
    for (int i = 0; i < 4; ++i)
        #pragma unroll
        for (int j = 0; j < 4; ++j) acc[i][j] = (floatx4)0.0f;

    #pragma unroll 2
    for (int kk = 0; kk < K_DIM; kk += 64) {
        __syncthreads();
        // ---- A regs -> LDS (lane-sequential granules: optimal banking) ----
        #pragma unroll
        for (int c = 0; c < 4; ++c)
            *(uint4*)(As + ((wid * 4 + c) * 64 + lane) * 8) = aR[c];
        // ---- B regs: transpose 8x4 + cvt -> LDS [n][k] swizzled ----
        #pragma unroll
        for (int i = 0; i < 4; ++i) {
            union { uint4 u; bf16_t h[8]; } pk;
            #pragma unroll
            for (int p = 0; p < 8; ++p)
                pk.h[p] = (bf16_t)(((const float*)&bR[p])[i]);
            int r = bn + i;
            *(uint4*)(Bs + ((r * 8 + (bkg ^ (r & 7))) * 8)) = pk.u;
        }
        // ---- prefetch next K-tile into regs (overlaps following MFMA) ----
        if (kk + 64 < K_DIM) {
            #pragma unroll
            for (int c = 0; c < 4; ++c)
                aR[c] = *(const uint4*)(aPtr + (size_t)c * 8 * K_DIM + (kk + 64));
            #pragma unroll
            for (int p = 0; p < 8; ++p)
                bR[p] = *(const float4*)(bPtr + (size_t)(kk + 64 + p) * N_DIM);
        }
        __syncthreads();
        // ---- MFMA ----
        #pragma unroll
        for (int ks = 0; ks < 2; ++ks) {
            bf16x8 af[4], bfr[4];
            #pragma unroll
            for (int i = 0; i < 4; ++i) {
                int r = wm + i * 16 + qm;
                int pg = r * 8 + ((ks * 4 + quad) ^ (r & 7));
                af[i] = *(const bf16x8*)(As + pg * 8);
            }
            #pragma unroll
            for (int j = 0; j < 4; ++j) {
                int r = wn + j * 16 + qm;
                int pg = r * 8 + ((ks * 4 + quad) ^ (r & 7));
                bfr[j] = *(const bf16x8*)(Bs + pg * 8);
            }
            #pragma unroll
            for (int i = 0; i < 4; ++i)
                #pragma unroll
                for (int j = 0; j < 4; ++j)
                    acc[i][j] = __builtin_amdgcn_mfma_f32_16x16x32_bf16(
                        bfr[j], af[i], acc[i][j], 0, 0, 0);   // swapped: C^T fragment
        }
    }

    // ---- epilogue: lane holds m = wm+i*16+qm (uniform guard), n = wn+j*16+quad*4+r ----
    #pragma unroll
    for (int i = 0; i < 4; ++i) {
        int gm = mt * 128 + wm + i * 16 + qm;
        if (gm < M_TOT) {
            #pragma unroll
            for (int j = 0; j < 4; ++j) {
                int ln0 = wn + j * 16 + quad * 4;        // local n (within 128-tile)
                float4 bz = *(const float4*)(be + ln0);
                float v[4];
                #pragma unroll
                for (int r = 0; r < 4; ++r) {
                    float t = acc[i][j][r] + ((const float*)&bz)[r];
                    if (GELU) t = 0.5f * t * (1.0f + erff(t * 0.70710678118654752f));
                    v[r] = t;
                }
                size_t idx = ((size_t)e * OSTR + gm) * N_DIM + nt * 128 + ln0;
                if (OUT_BF16) {
                    union { uint2 u; bf16_t h[4]; } pk;
                    pk.h[0] = (bf16_t)v[0]; pk.h[1] = (bf16_t)v[1];
                    pk.h[2] = (bf16_t)v[2]; pk.h[3] = (bf16_t)v[3];
                    *(uint2*)((bf16_t*)OutP + idx) = pk.u;
                } else {
                    float4 o; o.x = v[0]; o.y = v[1]; o.z = v[2]; o.w = v[3];
                    *(float4*)((float*)OutP + idx) = o;
                }
            }
        }
    }
}

// ---------------- K7: gather + mean over the two slots
__global__ __launch_bounds__(256) void k_gather(const float* __restrict__ y,
        const int* __restrict__ e_arr, const int* __restrict__ pos_arr,
        float* __restrict__ out)
{
    int tid = threadIdx.x;
    int t = blockIdx.x * 4 + (tid >> 6);
    int lane = tid & 63;
    float a[8];
    #pragma unroll
    for (int i = 0; i < 8; ++i) a[i] = 0.0f;
    #pragma unroll
    for (int k = 0; k < 2; ++k) {
        int s = 2 * t + k;
        int e = e_arr[s], p = pos_arr[s];
        if (p < CAP) {
            const float* yr = y + ((size_t)e * CAP + p) * DM + lane * 8;
            float4 f0 = *(const float4*)yr;
            float4 f1 = *(const float4*)(yr + 4);
            a[0] += f0.x; a[1] += f0.y; a[2] += f0.z; a[3] += f0.w;
            a[4] += f1.x; a[5] += f1.y; a[6] += f1.z; a[7] += f1.w;
        }
    }
    float4 o0, o1;
    o0.x = a[0] * 0.5f; o0.y = a[1] * 0.5f; o0.z = a[2] * 0.5f; o0.w = a[3] * 0.5f;
    o1.x = a[4] * 0.5f; o1.y = a[5] * 0.5f; o1.z = a[6] * 0.5f; o1.w = a[7] * 0.5f;
    float* orow = out + (size_t)t * DM + lane * 8;
    *(float4*)orow = o0;
    *(float4*)(orow + 4) = o1;
}

extern "C" void kernel_launch(void* const* d_in, const int* in_sizes, int n_in,
                              void* d_out, int out_size, void* d_ws, size_t ws_size,
                              hipStream_t stream)
{
    const float* x  = (const float*)d_in[0];
    const float* Wh = (const float*)d_in[1];
    const float* W1 = (const float*)d_in[2];
    const float* b1 = (const float*)d_in[3];
    const float* W2 = (const float*)d_in[4];
    const float* b2 = (const float*)d_in[5];
    float* out = (float*)d_out;

    char* p = (char*)d_ws;
    int*    e_arr  = (int*)p;    p += (size_t)NSLOT * 4;
    int*    rank_a = (int*)p;    p += (size_t)NSLOT * 4;
    int*    hist_g = (int*)p;    p += (size_t)64 * 64 * 4;
    int*    pos_a  = (int*)p;    p += (size_t)NSLOT * 4;
    int*    inv    = (int*)p;    p += (size_t)NEXP * CAP * 4;
    // buf (bf16, 25.2MB) and ybuf (fp32, 41.9MB) overlap: buf dead before GEMM2 writes ybuf
    bf16_t* buf    = (bf16_t*)p;
    float*  ybuf   = (float*)p;  p += (size_t)NEXP * CAP * DM * 4;
    bf16_t* hbuf   = (bf16_t*)p; p += (size_t)NEXP * MP * DF * 2;

    k_scores<<<2048, 256, 0, stream>>>(x, Wh, e_arr, inv);
    k_hist<<<64, 256, 0, stream>>>(e_arr, rank_a, hist_g);
    k_pos<<<64, 256, 0, stream>>>(e_arr, rank_a, hist_g, pos_a, inv);
    k_buf<<<NEXP * MP / 4, 256, 0, stream>>>(x, inv, buf);

    // GEMM1: buf[e][384][512] @ W1[e][512][2048] -> gelu -> hbuf (bf16)
    gemm_fused<CAP, MP, DF, DM, true, true>
        <<<NEXP * 3 * (DF / 128), 256, 0, stream>>>(buf, W1, b1, (void*)hbuf);

    // GEMM2: hbuf[e][384][2048] @ W2[e][2048][512] -> ybuf (fp32)
    gemm_fused<CAP, CAP, DM, DF, false, false>
        <<<NEXP * 3 * (DM / 128), 256, 0, stream>>>(hbuf, W2, b2, (void*)ybuf);

    k_gather<<<2048, 256, 0, stream>>>(ybuf, e_arr, pos_a, out);
}